// Round 2
// baseline (965.692 us; speedup 1.0000x reference)
//
#include <hip/hip_runtime.h>
#include <hip/hip_bf16.h>
#include <math.h>

// ---------------------------------------------------------------------------
// GATEdgeNet: 2-layer GAT (single head, self-loops + reversed edges) followed
// by an edge MLP.  Structure:
//   1. CSR build grouped by dst over 2E+N directed edges (hist/scan/scatter)
//   2. h1 = x @ W_g1 ; as1/ad1 = h1 . a1_src / a1_dst
//   3. f1 = relu(softmax-agg(h1) + b_g1)          (one block per node)
//   4. h2 = f1 @ W_g2 ; as2/ad2
//   5. f2 = relu(softmax-agg(h2) + b_g2)
//   6. P1 = [x,f2] @ W_m1[0:128]; P2 = [x,f2] @ W_m1[128:256]  (4 acc-GEMMs)
//   7. per-edge: sigmoid( relu(P1[row]+P2[col]+dist@W3+b1) . W_m2 + b2 )
// ---------------------------------------------------------------------------

#define GIN 64
#define GHID 128
#define GOUT 64

// ---------------- CSR build ------------------------------------------------

__global__ void hist_kernel(const int* __restrict__ eidx, int* __restrict__ deg,
                            int nE, int n) {
  int tot = 2 * nE + n;
  for (int i = blockIdx.x * blockDim.x + threadIdx.x; i < tot;
       i += gridDim.x * blockDim.x) {
    int dst;
    if (i < nE) dst = eidx[2 * i + 1];
    else if (i < 2 * nE) dst = eidx[2 * (i - nE)];
    else dst = i - 2 * nE;
    atomicAdd(&deg[dst], 1);
  }
}

// single-block exclusive scan (1024 threads, shfl within waves)
__global__ void scan_kernel(const int* __restrict__ deg, int* __restrict__ offs,
                            int* __restrict__ cursor, int n) {
  __shared__ int wsum[16];
  __shared__ int carry_s;
  int tid = threadIdx.x;
  int lane = tid & 63, wv = tid >> 6;
  if (tid == 0) carry_s = 0;
  __syncthreads();
  for (int base = 0; base < n; base += 1024) {
    int i = base + tid;
    int v = (i < n) ? deg[i] : 0;
    int incl = v;
#pragma unroll
    for (int off = 1; off < 64; off <<= 1) {
      int t = __shfl_up(incl, off, 64);
      if (lane >= off) incl += t;
    }
    if (lane == 63) wsum[wv] = incl;
    __syncthreads();
    int carry = carry_s;
    int woff = 0;
    for (int w2 = 0; w2 < wv; ++w2) woff += wsum[w2];
    int excl = carry + woff + incl - v;
    if (i < n) { offs[i] = excl; cursor[i] = excl; }
    __syncthreads();  // all reads of carry_s / wsum for this iter are done
    if (tid == 0) {
      int tot = 0;
      for (int w2 = 0; w2 < 16; ++w2) tot += wsum[w2];
      carry_s = carry + tot;
    }
    __syncthreads();  // carry_s updated & wsum read BEFORE next iter overwrites
  }
  if (threadIdx.x == 0) offs[n] = carry_s;
}

__global__ void scatter_kernel(const int* __restrict__ eidx, int* __restrict__ cursor,
                               int* __restrict__ csr, int nE, int n) {
  int tot = 2 * nE + n;
  for (int i = blockIdx.x * blockDim.x + threadIdx.x; i < tot;
       i += gridDim.x * blockDim.x) {
    int src, dst;
    if (i < nE)          { src = eidx[2 * i];            dst = eidx[2 * i + 1]; }
    else if (i < 2 * nE) { src = eidx[2 * (i - nE) + 1]; dst = eidx[2 * (i - nE)]; }
    else                 { src = i - 2 * nE;             dst = src; }
    int pos = atomicAdd(&cursor[dst], 1);
    csr[pos] = src;
  }
}

// ---------------- generic fp32 GEMM (64x64 tile, 4x4 microtile) ------------

template <bool ACC>
__global__ __launch_bounds__(256) void gemm_f32(
    const float* __restrict__ A, const float* __restrict__ B,
    float* __restrict__ C, int M, int K, int lda, int ldb, int ldc) {
  __shared__ float As[32][65];
  __shared__ float Bs[32][64];
  int tid = threadIdx.x;
  int m0 = blockIdx.x * 64;
  int n0 = blockIdx.y * 64;
  int tx = tid & 15, ty = tid >> 4;
  float acc[4][4] = {};
  for (int k0 = 0; k0 < K; k0 += 32) {
#pragma unroll
    for (int r = 0; r < 2; ++r) {   // A tile 64x32
      int m = (tid >> 3) + r * 32;
      int k = (tid & 7) * 4;
      float4 v = make_float4(0.f, 0.f, 0.f, 0.f);
      int gm = m0 + m;
      if (gm < M) v = *reinterpret_cast<const float4*>(&A[(size_t)gm * lda + k0 + k]);
      As[k + 0][m] = v.x; As[k + 1][m] = v.y; As[k + 2][m] = v.z; As[k + 3][m] = v.w;
    }
#pragma unroll
    for (int r = 0; r < 2; ++r) {   // B tile 32x64
      int k = (tid >> 4) + r * 16;
      int nn = (tid & 15) * 4;
      float4 v = *reinterpret_cast<const float4*>(&B[(size_t)(k0 + k) * ldb + n0 + nn]);
      *reinterpret_cast<float4*>(&Bs[k][nn]) = v;
    }
    __syncthreads();
#pragma unroll
    for (int k = 0; k < 32; ++k) {
      float a[4], b[4];
#pragma unroll
      for (int i = 0; i < 4; ++i) a[i] = As[k][ty * 4 + i];
#pragma unroll
      for (int i = 0; i < 4; ++i) b[i] = Bs[k][tx * 4 + i];
#pragma unroll
      for (int i = 0; i < 4; ++i)
#pragma unroll
        for (int j = 0; j < 4; ++j) acc[i][j] += a[i] * b[j];
    }
    __syncthreads();
  }
#pragma unroll
  for (int i = 0; i < 4; ++i) {
    int gm = m0 + ty * 4 + i;
    if (gm >= M) continue;
    float* cp = &C[(size_t)gm * ldc + n0 + tx * 4];
    float4 nv;
    if (ACC) {
      float4 old = *reinterpret_cast<const float4*>(cp);
      nv = make_float4(old.x + acc[i][0], old.y + acc[i][1],
                       old.z + acc[i][2], old.w + acc[i][3]);
    } else {
      nv = make_float4(acc[i][0], acc[i][1], acc[i][2], acc[i][3]);
    }
    *reinterpret_cast<float4*>(cp) = nv;
  }
}

// ---------------- per-node attention dots ----------------------------------

template <int D>
__global__ void node_dots(const float* __restrict__ h, const float* __restrict__ av,
                          const float* __restrict__ bv, float* __restrict__ as_,
                          float* __restrict__ ad_, int n) {
  int g = blockIdx.x * blockDim.x + threadIdx.x;
  int node = g >> 6, lane = g & 63;
  if (node >= n) return;
  float s = 0.f, d = 0.f;
#pragma unroll
  for (int j = lane; j < D; j += 64) {
    float v = h[(size_t)node * D + j];
    s += v * av[j];
    d += v * bv[j];
  }
#pragma unroll
  for (int off = 32; off; off >>= 1) {
    s += __shfl_xor(s, off, 64);
    d += __shfl_xor(d, off, 64);
  }
  if (lane == 0) { as_[node] = s; ad_[node] = d; }
}

// ---------------- GAT softmax aggregation (one block per node) -------------

template <int D>  // blockDim.x == D
__global__ void gat_agg(const float* __restrict__ h, const float* __restrict__ as_,
                        const float* __restrict__ ad_, const int* __restrict__ offs,
                        const int* __restrict__ csr, const float* __restrict__ bias,
                        float* __restrict__ out, int n) {
  int node = blockIdx.x;
  if (node >= n) return;
  int j = threadIdx.x;
  int beg = offs[node], end = offs[node + 1];
  float adn = ad_[node];
  // phase A: max over incident edges (threads parallel over edges)
  float m = -1e30f;
  for (int i = beg + j; i < end; i += D) {
    float v = as_[csr[i]] + adn;
    v = (v > 0.f) ? v : 0.2f * v;
    m = fmaxf(m, v);
  }
#pragma unroll
  for (int off = 32; off; off >>= 1) m = fmaxf(m, __shfl_xor(m, off, 64));
  if constexpr (D > 64) {
    __shared__ float red[D / 64];
    if ((j & 63) == 0) red[j >> 6] = m;
    __syncthreads();
    m = red[0];
#pragma unroll
    for (int w = 1; w < D / 64; ++w) m = fmaxf(m, red[w]);
  }
  // phase B: serial edge loop; thread j owns column j
  float denom = 0.f, acc = 0.f;
  for (int i = beg; i < end; ++i) {
    int s = csr[i];
    float v = as_[s] + adn;
    v = (v > 0.f) ? v : 0.2f * v;
    float w = __expf(v - m);
    denom += w;
    acc += w * h[(size_t)s * D + j];
  }
  out[(size_t)node * D + j] = fmaxf(acc / (denom + 1e-16f) + bias[j], 0.f);
}

// ---------------- fused edge MLP -------------------------------------------

__global__ __launch_bounds__(256) void edge_mlp(
    const int* __restrict__ eidx, const float* __restrict__ dist,
    const float* __restrict__ P, const float* __restrict__ W3,
    const float* __restrict__ b1, const float* __restrict__ W2,
    const float* __restrict__ b2, float* __restrict__ out, int nE) {
  __shared__ float W3s[16 * 128];
  __shared__ float W2s[128];
  __shared__ float b1s[128];
  int tid = threadIdx.x;
  for (int idx = tid; idx < 16 * 128; idx += 256) W3s[idx] = W3[idx];
  if (tid < 128) { W2s[tid] = W2[tid]; b1s[tid] = b1[tid]; }
  float b2v = b2[0];
  __syncthreads();
  int lane = tid & 63, wv = tid >> 6;
  int j0 = 2 * lane, j1 = j0 + 1;
  for (int e = blockIdx.x * 4 + wv; e < nE; e += gridDim.x * 4) {
    int r = eidx[2 * e], c = eidx[2 * e + 1];
    float2 v1 = *reinterpret_cast<const float2*>(&P[(size_t)r * 256 + j0]);
    float2 v2 = *reinterpret_cast<const float2*>(&P[(size_t)c * 256 + 128 + j0]);
    const float* db = &dist[(size_t)e * 16];
    float d[16];
#pragma unroll
    for (int k = 0; k < 16; ++k) d[k] = db[k];
    float a0 = v1.x + v2.x + b1s[j0];
    float a1 = v1.y + v2.y + b1s[j1];
#pragma unroll
    for (int k = 0; k < 16; ++k) {
      a0 += d[k] * W3s[k * 128 + j0];
      a1 += d[k] * W3s[k * 128 + j1];
    }
    float p = fmaxf(a0, 0.f) * W2s[j0] + fmaxf(a1, 0.f) * W2s[j1];
#pragma unroll
    for (int off = 32; off; off >>= 1) p += __shfl_xor(p, off, 64);
    if (lane == 0) {
      float z = p + b2v;
      out[e] = 1.f / (1.f + __expf(-z));
    }
  }
}

// ---------------- launch ---------------------------------------------------

extern "C" void kernel_launch(void* const* d_in, const int* in_sizes, int n_in,
                              void* d_out, int out_size, void* d_ws, size_t ws_size,
                              hipStream_t stream) {
  const float* x       = (const float*)d_in[0];
  const int*   eidx    = (const int*)d_in[1];
  const float* dist    = (const float*)d_in[2];
  const float* W_g1    = (const float*)d_in[3];
  const float* a1_src  = (const float*)d_in[4];
  const float* a1_dst  = (const float*)d_in[5];
  const float* b_g1    = (const float*)d_in[6];
  const float* W_g2    = (const float*)d_in[7];
  const float* a2_src  = (const float*)d_in[8];
  const float* a2_dst  = (const float*)d_in[9];
  const float* b_g2    = (const float*)d_in[10];
  const float* W_m1    = (const float*)d_in[11];
  const float* b_m1    = (const float*)d_in[12];
  const float* W_m2    = (const float*)d_in[13];
  const float* b_m2    = (const float*)d_in[14];
  float* out = (float*)d_out;

  const int n  = in_sizes[0] / GIN;   // 50000
  const int nE = in_sizes[1] / 2;     // 800000
  const int ndir = 2 * nE + n;        // 1,650,000

  // workspace layout
  char* w = (char*)d_ws;
  size_t off = 0;
  auto alloc = [&](size_t bytes) {
    size_t o = off;
    off += (bytes + 255) & ~(size_t)255;
    return o;
  };
  size_t o_deg    = alloc((size_t)n * 4);
  size_t o_offs   = alloc((size_t)(n + 1) * 4);
  size_t o_cursor = alloc((size_t)n * 4);
  size_t o_as1    = alloc((size_t)n * 4);
  size_t o_ad1    = alloc((size_t)n * 4);
  size_t o_as2    = alloc((size_t)n * 4);
  size_t o_ad2    = alloc((size_t)n * 4);
  size_t o_csr    = alloc((size_t)ndir * 4);
  size_t o_h2     = alloc((size_t)n * GOUT * 4);
  size_t o_f2     = alloc((size_t)n * GOUT * 4);
  size_t o_bigA   = alloc((size_t)n * GHID * 4);  // h1, later P[:, :128] region
  size_t o_bigB   = alloc((size_t)n * GHID * 4);  // f1, later P[:, 128:] region
  // NOTE: n*GHID*4 = 25,600,000 is 256-aligned, so bigA/bigB are contiguous.

  int*   deg    = (int*)(w + o_deg);
  int*   offs   = (int*)(w + o_offs);
  int*   cursor = (int*)(w + o_cursor);
  float* as1    = (float*)(w + o_as1);
  float* ad1    = (float*)(w + o_ad1);
  float* as2    = (float*)(w + o_as2);
  float* ad2    = (float*)(w + o_ad2);
  int*   csr    = (int*)(w + o_csr);
  float* h2     = (float*)(w + o_h2);
  float* f2     = (float*)(w + o_f2);
  float* h1     = (float*)(w + o_bigA);
  float* f1     = (float*)(w + o_bigB);
  float* P      = (float*)(w + o_bigA);  // 50000 x 256, overlays h1+f1 (both dead)

  // 1. CSR build
  hipMemsetAsync(deg, 0, (size_t)n * 4, stream);
  hist_kernel<<<2048, 256, 0, stream>>>(eidx, deg, nE, n);
  scan_kernel<<<1, 1024, 0, stream>>>(deg, offs, cursor, n);
  scatter_kernel<<<2048, 256, 0, stream>>>(eidx, cursor, csr, nE, n);

  const int mtiles = (n + 63) / 64;  // 782

  // 2. h1 = x @ W_g1  (50000x64 @ 64x128)
  gemm_f32<false><<<dim3(mtiles, 2), 256, 0, stream>>>(x, W_g1, h1, n, GIN, GIN, GHID, GHID);
  node_dots<GHID><<<(n * 64 + 255) / 256, 256, 0, stream>>>(h1, a1_src, a1_dst, as1, ad1, n);

  // 3. f1 = relu(agg(h1) + b_g1)
  gat_agg<GHID><<<n, GHID, 0, stream>>>(h1, as1, ad1, offs, csr, b_g1, f1, n);

  // 4. h2 = f1 @ W_g2  (50000x128 @ 128x64)
  gemm_f32<false><<<dim3(mtiles, 1), 256, 0, stream>>>(f1, W_g2, h2, n, GHID, GHID, GOUT, GOUT);
  node_dots<GOUT><<<(n * 64 + 255) / 256, 256, 0, stream>>>(h2, a2_src, a2_dst, as2, ad2, n);

  // 5. f2 = relu(agg(h2) + b_g2)
  gat_agg<GOUT><<<n, GOUT, 0, stream>>>(h2, as2, ad2, offs, csr, b_g2, f2, n);

  // 6. P = [x,f2] @ W_m1[0:256] split into 4 accumulate GEMMs.
  //    P[:, :128] = x @ W_m1[0:64]   + f2 @ W_m1[64:128]
  //    P[:,128:]  = x @ W_m1[128:192] + f2 @ W_m1[192:256]
  gemm_f32<false><<<dim3(mtiles, 2), 256, 0, stream>>>(x,  W_m1,             P,       n, GIN, GIN,  GHID, 256);
  gemm_f32<true ><<<dim3(mtiles, 2), 256, 0, stream>>>(f2, W_m1 + 64 * 128,  P,       n, GIN, GOUT, GHID, 256);
  gemm_f32<false><<<dim3(mtiles, 2), 256, 0, stream>>>(x,  W_m1 + 128 * 128, P + 128, n, GIN, GIN,  GHID, 256);
  gemm_f32<true ><<<dim3(mtiles, 2), 256, 0, stream>>>(f2, W_m1 + 192 * 128, P + 128, n, GIN, GOUT, GHID, 256);

  // 7. fused edge MLP + sigmoid
  edge_mlp<<<4096, 256, 0, stream>>>(eidx, dist, P, W_m1 + 256 * 128, b_m1, W_m2, b_m2,
                                     out, nE);
}

// Round 3
// 936.736 us; speedup vs baseline: 1.0309x; 1.0309x over previous
//
#include <hip/hip_runtime.h>
#include <hip/hip_bf16.h>
#include <math.h>

// ---------------------------------------------------------------------------
// GATEdgeNet. fp32 everywhere EXCEPT the three gathered tensors (h1, h2, P),
// which are stored bf16 to halve random-gather bytes. Scores as/ad computed
// from fp32 h, so softmax weights stay fp32-exact.
//   1. CSR build grouped by dst (hist / hierarchical scan / scatter)
//   2. h1 = x @ W_g1  (fp32 + bf16 dual store) ; as1/ad1 from fp32 h1
//   3. f1 = relu(agg(bf16 h1) + b_g1)             (one wave per node)
//   4. h2 = f1 @ W_g2 (dual store) ; as2/ad2
//   5. xf[:,0:64] = x ; xf[:,64:128] = f2 = relu(agg(bf16 h2) + b_g2)
//   6. Pb = bf16( xf @ W_m1[0:128] | xf @ W_m1[128:256] )   (2 GEMMs)
//   7. per-edge: sigmoid( relu(P1[r]+P2[c]+dist@W3+b1) . W_m2 + b2 )
// ---------------------------------------------------------------------------

#define GIN 64
#define GHID 128
#define GOUT 64

typedef unsigned int u32;
typedef unsigned short u16;

__device__ __forceinline__ float bflo(u32 u) {
  union { u32 i; float f; } c; c.i = u << 16; return c.f;
}
__device__ __forceinline__ float bfhi(u32 u) {
  union { u32 i; float f; } c; c.i = u & 0xffff0000u; return c.f;
}
__device__ __forceinline__ float bf1(u16 u) {
  union { u32 i; float f; } c; c.i = ((u32)u) << 16; return c.f;
}
__device__ __forceinline__ u16 f2bf(float x) {
  __hip_bfloat16 h = __float2bfloat16(x);
  return *reinterpret_cast<u16*>(&h);
}

// ---------------- CSR build ------------------------------------------------

__global__ void hist_kernel(const int* __restrict__ eidx, int* __restrict__ deg,
                            int nE, int n) {
  int tot = 2 * nE + n;
  for (int i = blockIdx.x * blockDim.x + threadIdx.x; i < tot;
       i += gridDim.x * blockDim.x) {
    int dst;
    if (i < nE) dst = eidx[2 * i + 1];
    else if (i < 2 * nE) dst = eidx[2 * (i - nE)];
    else dst = i - 2 * nE;
    atomicAdd(&deg[dst], 1);
  }
}

#define SCAN_CHUNK 1024
// per-1024-chunk sums
__global__ void scan_partial(const int* __restrict__ deg, int* __restrict__ bsum,
                             int n) {
  int b = blockIdx.x, tid = threadIdx.x;  // 256 threads
  int base = b * SCAN_CHUNK + tid * 4;
  int s = 0;
#pragma unroll
  for (int c = 0; c < 4; ++c) { int i = base + c; if (i < n) s += deg[i]; }
#pragma unroll
  for (int off = 32; off; off >>= 1) s += __shfl_xor(s, off, 64);
  __shared__ int ws[4];
  if ((tid & 63) == 0) ws[tid >> 6] = s;
  __syncthreads();
  if (tid == 0) bsum[b] = ws[0] + ws[1] + ws[2] + ws[3];
}
// single-wave exclusive scan of <=64 chunk sums
__global__ void scan_bsums(const int* __restrict__ bsum, int* __restrict__ bscan,
                           int* __restrict__ offs, int nb, int n) {
  int lane = threadIdx.x;
  int v = (lane < nb) ? bsum[lane] : 0;
  int incl = v;
#pragma unroll
  for (int off = 1; off < 64; off <<= 1) {
    int t = __shfl_up(incl, off, 64);
    if (lane >= off) incl += t;
  }
  if (lane < nb) bscan[lane] = incl - v;
  if (lane == 63) offs[n] = incl;
}
__global__ void scan_final(const int* __restrict__ deg, const int* __restrict__ bscan,
                           int* __restrict__ offs, int* __restrict__ cursor, int n) {
  int b = blockIdx.x, tid = threadIdx.x;
  int base = b * SCAN_CHUNK + tid * 4;
  int v[4]; int s = 0;
#pragma unroll
  for (int c = 0; c < 4; ++c) { int i = base + c; v[c] = (i < n) ? deg[i] : 0; s += v[c]; }
  int lane = tid & 63, wv = tid >> 6;
  int incl = s;
#pragma unroll
  for (int off = 1; off < 64; off <<= 1) {
    int t = __shfl_up(incl, off, 64);
    if (lane >= off) incl += t;
  }
  __shared__ int ws[4];
  if (lane == 63) ws[wv] = incl;
  __syncthreads();
  int woff = 0;
  for (int w2 = 0; w2 < wv; ++w2) woff += ws[w2];
  int excl = bscan[b] + woff + incl - s;
#pragma unroll
  for (int c = 0; c < 4; ++c) {
    int i = base + c;
    if (i < n) { offs[i] = excl; cursor[i] = excl; }
    excl += v[c];
  }
}

__global__ void scatter_kernel(const int* __restrict__ eidx, int* __restrict__ cursor,
                               int* __restrict__ csr, int nE, int n) {
  int tot = 2 * nE + n;
  for (int i = blockIdx.x * blockDim.x + threadIdx.x; i < tot;
       i += gridDim.x * blockDim.x) {
    int src, dst;
    if (i < nE)          { src = eidx[2 * i];            dst = eidx[2 * i + 1]; }
    else if (i < 2 * nE) { src = eidx[2 * (i - nE) + 1]; dst = eidx[2 * (i - nE)]; }
    else                 { src = i - 2 * nE;             dst = src; }
    int pos = atomicAdd(&cursor[dst], 1);
    csr[pos] = src;
  }
}

// ---------------- fp32 GEMM (64x64 tile, 4x4 microtile), dual-dtype store --

template <bool WF32, bool WBF16>
__global__ __launch_bounds__(256) void gemm_f32(
    const float* __restrict__ A, const float* __restrict__ B,
    float* __restrict__ Cf, u16* __restrict__ Cb,
    int M, int K, int lda, int ldb, int ldc, int ldcb) {
  __shared__ float As[32][68];   // 68: rows 16B-aligned -> ds_read_b128 on A frags
  __shared__ float Bs[32][64];
  int tid = threadIdx.x;
  int m0 = blockIdx.x * 64;
  int n0 = blockIdx.y * 64;
  int tx = tid & 15, ty = tid >> 4;
  float acc[4][4] = {};
  for (int k0 = 0; k0 < K; k0 += 32) {
#pragma unroll
    for (int r = 0; r < 2; ++r) {   // A tile 64x32
      int m = (tid >> 3) + r * 32;
      int k = (tid & 7) * 4;
      float4 v = make_float4(0.f, 0.f, 0.f, 0.f);
      int gm = m0 + m;
      if (gm < M) v = *reinterpret_cast<const float4*>(&A[(size_t)gm * lda + k0 + k]);
      As[k + 0][m] = v.x; As[k + 1][m] = v.y; As[k + 2][m] = v.z; As[k + 3][m] = v.w;
    }
#pragma unroll
    for (int r = 0; r < 2; ++r) {   // B tile 32x64
      int k = (tid >> 4) + r * 16;
      int nn = (tid & 15) * 4;
      float4 v = *reinterpret_cast<const float4*>(&B[(size_t)(k0 + k) * ldb + n0 + nn]);
      *reinterpret_cast<float4*>(&Bs[k][nn]) = v;
    }
    __syncthreads();
#pragma unroll
    for (int k = 0; k < 32; ++k) {
      float a[4], b[4];
#pragma unroll
      for (int i = 0; i < 4; ++i) a[i] = As[k][ty * 4 + i];
#pragma unroll
      for (int i = 0; i < 4; ++i) b[i] = Bs[k][tx * 4 + i];
#pragma unroll
      for (int i = 0; i < 4; ++i)
#pragma unroll
        for (int j = 0; j < 4; ++j) acc[i][j] += a[i] * b[j];
    }
    __syncthreads();
  }
#pragma unroll
  for (int i = 0; i < 4; ++i) {
    int gm = m0 + ty * 4 + i;
    if (gm >= M) continue;
    if (WF32) {
      float* cp = &Cf[(size_t)gm * ldc + n0 + tx * 4];
      *reinterpret_cast<float4*>(cp) =
          make_float4(acc[i][0], acc[i][1], acc[i][2], acc[i][3]);
    }
    if (WBF16) {
      u16* bp = &Cb[(size_t)gm * ldcb + n0 + tx * 4];
      *reinterpret_cast<ushort4*>(bp) = make_ushort4(
          f2bf(acc[i][0]), f2bf(acc[i][1]), f2bf(acc[i][2]), f2bf(acc[i][3]));
    }
  }
}

// ---------------- per-node attention dots (fp32 h) -------------------------

template <int D>
__global__ void node_dots(const float* __restrict__ h, const float* __restrict__ av,
                          const float* __restrict__ bv, float* __restrict__ as_,
                          float* __restrict__ ad_, int n) {
  int g = blockIdx.x * blockDim.x + threadIdx.x;
  int node = g >> 6, lane = g & 63;
  if (node >= n) return;
  float s = 0.f, d = 0.f;
#pragma unroll
  for (int j = lane; j < D; j += 64) {
    float v = h[(size_t)node * D + j];
    s += v * av[j];
    d += v * bv[j];
  }
#pragma unroll
  for (int off = 32; off; off >>= 1) {
    s += __shfl_xor(s, off, 64);
    d += __shfl_xor(d, off, 64);
  }
  if (lane == 0) { as_[node] = s; ad_[node] = d; }
}

// ---------------- GAT softmax agg, D=128 (one wave/node, bf16 rows) --------

__global__ __launch_bounds__(256) void gat_agg1(
    const u16* __restrict__ hb, const float* __restrict__ as_,
    const float* __restrict__ ad_, const int* __restrict__ offs,
    const int* __restrict__ csr, const float* __restrict__ bias,
    float* __restrict__ out, int n) {
  int node = blockIdx.x * 4 + (threadIdx.x >> 6);
  if (node >= n) return;
  int lane = threadIdx.x & 63;
  int beg = offs[node], end = offs[node + 1];
  float adn = ad_[node];
  float m = -1e30f;
  for (int i = beg + lane; i < end; i += 64) {
    float v = as_[csr[i]] + adn;
    v = (v > 0.f) ? v : 0.2f * v;
    m = fmaxf(m, v);
  }
#pragma unroll
  for (int off = 32; off; off >>= 1) m = fmaxf(m, __shfl_xor(m, off, 64));
  float denom = 0.f, a0 = 0.f, a1 = 0.f;
  int lcol = 2 * lane;
  // 1-deep software pipeline over the serial edge loop
  int i = beg;
  int s = csr[i];
  u32 pv = *reinterpret_cast<const u32*>(&hb[(size_t)s * 128 + lcol]);
  float e = as_[s] + adn;
  for (++i; i < end; ++i) {
    int s2 = csr[i];
    u32 pv2 = *reinterpret_cast<const u32*>(&hb[(size_t)s2 * 128 + lcol]);
    float e2 = as_[s2] + adn;
    e = (e > 0.f) ? e : 0.2f * e;
    float wgt = __expf(e - m);
    denom += wgt; a0 += wgt * bflo(pv); a1 += wgt * bfhi(pv);
    pv = pv2; e = e2;
  }
  e = (e > 0.f) ? e : 0.2f * e;
  float wgt = __expf(e - m);
  denom += wgt; a0 += wgt * bflo(pv); a1 += wgt * bfhi(pv);
  float inv = 1.f / (denom + 1e-16f);
  float2 o;
  o.x = fmaxf(a0 * inv + bias[lcol], 0.f);
  o.y = fmaxf(a1 * inv + bias[lcol + 1], 0.f);
  *reinterpret_cast<float2*>(&out[(size_t)node * 128 + lcol]) = o;
}

// ---------------- GAT softmax agg, D=64 -> writes into xf[:,64:128] --------

__global__ __launch_bounds__(256) void gat_agg2(
    const u16* __restrict__ hb, const float* __restrict__ as_,
    const float* __restrict__ ad_, const int* __restrict__ offs,
    const int* __restrict__ csr, const float* __restrict__ bias,
    float* __restrict__ xf, int n) {
  int node = blockIdx.x * 4 + (threadIdx.x >> 6);
  if (node >= n) return;
  int lane = threadIdx.x & 63;
  int beg = offs[node], end = offs[node + 1];
  float adn = ad_[node];
  float m = -1e30f;
  for (int i = beg + lane; i < end; i += 64) {
    float v = as_[csr[i]] + adn;
    v = (v > 0.f) ? v : 0.2f * v;
    m = fmaxf(m, v);
  }
#pragma unroll
  for (int off = 32; off; off >>= 1) m = fmaxf(m, __shfl_xor(m, off, 64));
  float denom = 0.f, a0 = 0.f;
  int i = beg;
  int s = csr[i];
  u16 hv = hb[(size_t)s * 64 + lane];
  float e = as_[s] + adn;
  for (++i; i < end; ++i) {
    int s2 = csr[i];
    u16 hv2 = hb[(size_t)s2 * 64 + lane];
    float e2 = as_[s2] + adn;
    e = (e > 0.f) ? e : 0.2f * e;
    float wgt = __expf(e - m);
    denom += wgt; a0 += wgt * bf1(hv);
    hv = hv2; e = e2;
  }
  e = (e > 0.f) ? e : 0.2f * e;
  float wgt = __expf(e - m);
  denom += wgt; a0 += wgt * bf1(hv);
  float inv = 1.f / (denom + 1e-16f);
  xf[(size_t)node * 128 + 64 + lane] = fmaxf(a0 * inv + bias[lane], 0.f);
}

// ---------------- pack x into xf[:,0:64] -----------------------------------

__global__ void xcopy(const float* __restrict__ x, float* __restrict__ xf, int n) {
  int i = blockIdx.x * blockDim.x + threadIdx.x;
  int tot = n * 16;  // 16 float4 per node row (64 floats)
  if (i >= tot) return;
  int node = i >> 4, q = i & 15;
  float4 v = reinterpret_cast<const float4*>(x)[(size_t)node * 16 + q];
  reinterpret_cast<float4*>(xf)[(size_t)node * 32 + q] = v;
}

// ---------------- fused edge MLP (bf16 P gather) ---------------------------

__global__ __launch_bounds__(256) void edge_mlp(
    const int* __restrict__ eidx, const float* __restrict__ dist,
    const u16* __restrict__ Pb, const float* __restrict__ W3,
    const float* __restrict__ b1, const float* __restrict__ W2,
    const float* __restrict__ b2, float* __restrict__ out, int nE) {
  __shared__ float2 W3s[16][64];
  __shared__ float2 b1s[64];
  __shared__ float2 w2s[64];
  int tid = threadIdx.x;
  for (int idx = tid; idx < 16 * 64; idx += 256) {
    int k = idx >> 6, j = idx & 63;
    W3s[k][j] = make_float2(W3[k * 128 + 2 * j], W3[k * 128 + 2 * j + 1]);
  }
  if (tid < 64) {
    b1s[tid] = make_float2(b1[2 * tid], b1[2 * tid + 1]);
    w2s[tid] = make_float2(W2[2 * tid], W2[2 * tid + 1]);
  }
  float b2v = b2[0];
  __syncthreads();
  int lane = tid & 63, wv = tid >> 6;
  float2 b1v = b1s[lane], w2v = w2s[lane];
  for (int e = blockIdx.x * 4 + wv; e < nE; e += gridDim.x * 4) {
    int r = eidx[2 * e], c = eidx[2 * e + 1];
    u32 p1 = *reinterpret_cast<const u32*>(&Pb[(size_t)r * 256 + 2 * lane]);
    u32 p2 = *reinterpret_cast<const u32*>(&Pb[(size_t)c * 256 + 128 + 2 * lane]);
    float a0 = bflo(p1) + bflo(p2) + b1v.x;
    float a1 = bfhi(p1) + bfhi(p2) + b1v.y;
    const float* db = &dist[(size_t)e * 16];
#pragma unroll
    for (int k = 0; k < 16; ++k) {
      float d = db[k];
      float2 w3 = W3s[k][lane];
      a0 += d * w3.x;
      a1 += d * w3.y;
    }
    float p = fmaxf(a0, 0.f) * w2v.x + fmaxf(a1, 0.f) * w2v.y;
#pragma unroll
    for (int off = 32; off; off >>= 1) p += __shfl_xor(p, off, 64);
    if (lane == 0) out[e] = 1.f / (1.f + __expf(-(p + b2v)));
  }
}

// ---------------- launch ---------------------------------------------------

extern "C" void kernel_launch(void* const* d_in, const int* in_sizes, int n_in,
                              void* d_out, int out_size, void* d_ws, size_t ws_size,
                              hipStream_t stream) {
  const float* x      = (const float*)d_in[0];
  const int*   eidx   = (const int*)d_in[1];
  const float* dist   = (const float*)d_in[2];
  const float* W_g1   = (const float*)d_in[3];
  const float* a1_src = (const float*)d_in[4];
  const float* a1_dst = (const float*)d_in[5];
  const float* b_g1   = (const float*)d_in[6];
  const float* W_g2   = (const float*)d_in[7];
  const float* a2_src = (const float*)d_in[8];
  const float* a2_dst = (const float*)d_in[9];
  const float* b_g2   = (const float*)d_in[10];
  const float* W_m1   = (const float*)d_in[11];
  const float* b_m1   = (const float*)d_in[12];
  const float* W_m2   = (const float*)d_in[13];
  const float* b_m2   = (const float*)d_in[14];
  float* out = (float*)d_out;

  const int n  = in_sizes[0] / GIN;   // 50000
  const int nE = in_sizes[1] / 2;     // 800000
  const int ndir = 2 * nE + n;        // 1,650,000

  char* w = (char*)d_ws;
  size_t off = 0;
  auto alloc = [&](size_t bytes) {
    size_t o = off;
    off += (bytes + 255) & ~(size_t)255;
    return o;
  };
  size_t o_deg    = alloc((size_t)n * 4);
  size_t o_offs   = alloc((size_t)(n + 1) * 4);
  size_t o_cursor = alloc((size_t)n * 4);
  size_t o_as1    = alloc((size_t)n * 4);
  size_t o_ad1    = alloc((size_t)n * 4);
  size_t o_as2    = alloc((size_t)n * 4);
  size_t o_ad2    = alloc((size_t)n * 4);
  size_t o_bsum   = alloc(64 * 4);
  size_t o_bscan  = alloc(64 * 4);
  size_t o_csr    = alloc((size_t)ndir * 4);
  size_t o_A      = alloc((size_t)n * GHID * 4);  // h1f -> {h2f,h2b} -> Pb
  size_t o_B      = alloc((size_t)n * GHID * 2);  // h1b
  size_t o_C      = alloc((size_t)n * GHID * 4);  // f1 -> xf
  (void)ws_size;

  int*   deg    = (int*)(w + o_deg);
  int*   offs   = (int*)(w + o_offs);
  int*   cursor = (int*)(w + o_cursor);
  float* as1    = (float*)(w + o_as1);
  float* ad1    = (float*)(w + o_ad1);
  float* as2    = (float*)(w + o_as2);
  float* ad2    = (float*)(w + o_ad2);
  int*   bsum   = (int*)(w + o_bsum);
  int*   bscan  = (int*)(w + o_bscan);
  int*   csr    = (int*)(w + o_csr);
  float* h1f    = (float*)(w + o_A);
  u16*   h1b    = (u16*)(w + o_B);
  float* f1     = (float*)(w + o_C);
  float* h2f    = (float*)(w + o_A);                       // overlays dead h1f
  u16*   h2b    = (u16*)(w + o_A + (size_t)n * GOUT * 4);  // after h2f
  float* xf     = (float*)(w + o_C);                       // overlays dead f1
  u16*   Pb     = (u16*)(w + o_A);                         // overlays dead h2f/h2b

  // 1. CSR build
  hipMemsetAsync(deg, 0, (size_t)n * 4, stream);
  hist_kernel<<<2048, 256, 0, stream>>>(eidx, deg, nE, n);
  int nb = (n + SCAN_CHUNK - 1) / SCAN_CHUNK;  // 49 (<=64 required)
  scan_partial<<<nb, 256, 0, stream>>>(deg, bsum, n);
  scan_bsums<<<1, 64, 0, stream>>>(bsum, bscan, offs, nb, n);
  scan_final<<<nb, 256, 0, stream>>>(deg, bscan, offs, cursor, n);
  scatter_kernel<<<2048, 256, 0, stream>>>(eidx, cursor, csr, nE, n);

  const int mtiles = (n + 63) / 64;  // 782

  // 2. h1 = x @ W_g1 (dual store), scores from fp32
  gemm_f32<true, true><<<dim3(mtiles, 2), 256, 0, stream>>>(
      x, W_g1, h1f, h1b, n, GIN, GIN, GHID, GHID, GHID);
  node_dots<GHID><<<(n * 64 + 255) / 256, 256, 0, stream>>>(h1f, a1_src, a1_dst, as1, ad1, n);

  // 3. f1 = relu(agg(h1b) + b_g1)
  gat_agg1<<<(n + 3) / 4, 256, 0, stream>>>(h1b, as1, ad1, offs, csr, b_g1, f1, n);

  // 4. h2 = f1 @ W_g2 (dual store)
  gemm_f32<true, true><<<dim3(mtiles, 1), 256, 0, stream>>>(
      f1, W_g2, h2f, h2b, n, GHID, GHID, GOUT, GOUT, GOUT);
  node_dots<GOUT><<<(n * 64 + 255) / 256, 256, 0, stream>>>(h2f, a2_src, a2_dst, as2, ad2, n);

  // 5. xf = [x | f2]   (xcopy after gemm2 — xf overlays f1)
  xcopy<<<(n * 16 + 255) / 256, 256, 0, stream>>>(x, xf, n);
  gat_agg2<<<(n + 3) / 4, 256, 0, stream>>>(h2b, as2, ad2, offs, csr, b_g2, xf, n);

  // 6. Pb = bf16([xf @ W_m1[0:128] | xf @ W_m1[128:256]])
  gemm_f32<false, true><<<dim3(mtiles, 2), 256, 0, stream>>>(
      xf, W_m1, nullptr, Pb, n, GHID, GHID, GHID, 0, 256);
  gemm_f32<false, true><<<dim3(mtiles, 2), 256, 0, stream>>>(
      xf, W_m1 + 128 * 128, nullptr, Pb + 128, n, GHID, GHID, GHID, 0, 256);

  // 7. fused edge MLP + sigmoid
  edge_mlp<<<4096, 256, 0, stream>>>(eidx, dist, Pb, W_m1 + 256 * 128, b_m1, W_m2, b_m2,
                                     out, nE);
}

// Round 4
// 719.090 us; speedup vs baseline: 1.3429x; 1.3027x over previous
//
#include <hip/hip_runtime.h>
#include <hip/hip_bf16.h>
#include <math.h>

// ---------------------------------------------------------------------------
// GATEdgeNet. fp32 compute; gathered tensors (h1, h2, P) stored bf16.
//   1. CSR build grouped by dst (hist / hierarchical scan / scatter)
//   2. h1b = bf16(x @ W_g1); as1/ad1 fused in GEMM epilogue (fp32-exact)
//   3. f1 = relu(agg(h1b) + b_g1)        (1 block/4 nodes, 2 edges in flight)
//   4. h2b = bf16(f1 @ W_g2); as2/ad2 fused
//   5. f2 = relu(agg(h2b) + b_g2)        (4 edges in flight)
//   6. Pb = bf16([x|f2] @ W_m1[0:256])   (one dispatch, k-split A source)
//   7. edge MLP: 4 edges/wave, 16 lanes/edge
// ---------------------------------------------------------------------------

#define GIN 64
#define GHID 128
#define GOUT 64

typedef unsigned int u32;
typedef unsigned short u16;

__device__ __forceinline__ float bflo(u32 u) {
  union { u32 i; float f; } c; c.i = u << 16; return c.f;
}
__device__ __forceinline__ float bfhi(u32 u) {
  union { u32 i; float f; } c; c.i = u & 0xffff0000u; return c.f;
}
__device__ __forceinline__ u16 f2bf(float x) {
  __hip_bfloat16 h = __float2bfloat16(x);
  return *reinterpret_cast<u16*>(&h);
}

// ---------------- CSR build ------------------------------------------------

__global__ void hist_kernel(const int* __restrict__ eidx, int* __restrict__ deg,
                            int nE, int n) {
  int tot = 2 * nE + n;
  for (int i = blockIdx.x * blockDim.x + threadIdx.x; i < tot;
       i += gridDim.x * blockDim.x) {
    int dst;
    if (i < nE) dst = eidx[2 * i + 1];
    else if (i < 2 * nE) dst = eidx[2 * (i - nE)];
    else dst = i - 2 * nE;
    atomicAdd(&deg[dst], 1);
  }
}

#define SCAN_CHUNK 1024
__global__ void scan_partial(const int* __restrict__ deg, int* __restrict__ bsum,
                             int n) {
  int b = blockIdx.x, tid = threadIdx.x;  // 256 threads
  int base = b * SCAN_CHUNK + tid * 4;
  int s = 0;
#pragma unroll
  for (int c = 0; c < 4; ++c) { int i = base + c; if (i < n) s += deg[i]; }
#pragma unroll
  for (int off = 32; off; off >>= 1) s += __shfl_xor(s, off, 64);
  __shared__ int ws[4];
  if ((tid & 63) == 0) ws[tid >> 6] = s;
  __syncthreads();
  if (tid == 0) bsum[b] = ws[0] + ws[1] + ws[2] + ws[3];
}
__global__ void scan_bsums(const int* __restrict__ bsum, int* __restrict__ bscan,
                           int* __restrict__ offs, int nb, int n) {
  int lane = threadIdx.x;
  int v = (lane < nb) ? bsum[lane] : 0;
  int incl = v;
#pragma unroll
  for (int off = 1; off < 64; off <<= 1) {
    int t = __shfl_up(incl, off, 64);
    if (lane >= off) incl += t;
  }
  if (lane < nb) bscan[lane] = incl - v;
  if (lane == 63) offs[n] = incl;
}
__global__ void scan_final(const int* __restrict__ deg, const int* __restrict__ bscan,
                           int* __restrict__ offs, int* __restrict__ cursor, int n) {
  int b = blockIdx.x, tid = threadIdx.x;
  int base = b * SCAN_CHUNK + tid * 4;
  int v[4]; int s = 0;
#pragma unroll
  for (int c = 0; c < 4; ++c) { int i = base + c; v[c] = (i < n) ? deg[i] : 0; s += v[c]; }
  int lane = tid & 63, wv = tid >> 6;
  int incl = s;
#pragma unroll
  for (int off = 1; off < 64; off <<= 1) {
    int t = __shfl_up(incl, off, 64);
    if (lane >= off) incl += t;
  }
  __shared__ int ws[4];
  if (lane == 63) ws[wv] = incl;
  __syncthreads();
  int woff = 0;
  for (int w2 = 0; w2 < wv; ++w2) woff += ws[w2];
  int excl = bscan[b] + woff + incl - s;
#pragma unroll
  for (int c = 0; c < 4; ++c) {
    int i = base + c;
    if (i < n) { offs[i] = excl; cursor[i] = excl; }
    excl += v[c];
  }
}

__global__ void scatter_kernel(const int* __restrict__ eidx, int* __restrict__ cursor,
                               int* __restrict__ csr, int nE, int n) {
  int tot = 2 * nE + n;
  for (int i = blockIdx.x * blockDim.x + threadIdx.x; i < tot;
       i += gridDim.x * blockDim.x) {
    int src, dst;
    if (i < nE)          { src = eidx[2 * i];            dst = eidx[2 * i + 1]; }
    else if (i < 2 * nE) { src = eidx[2 * (i - nE) + 1]; dst = eidx[2 * (i - nE)]; }
    else                 { src = i - 2 * nE;             dst = src; }
    int pos = atomicAdd(&cursor[dst], 1);
    csr[pos] = src;
  }
}

// ---- fp32 GEMM, bf16 store, optional fused score dots, k-split A source ----

template <bool SCORES>
__global__ __launch_bounds__(256) void gemm_bf(
    const float* __restrict__ A, const float* __restrict__ A2, int ksp,
    int lda, int lda2,
    const float* __restrict__ B, int bskip, int ldb,
    u16* __restrict__ Cb, int ldcb,
    const float* __restrict__ av, const float* __restrict__ bv,
    float* __restrict__ as_, float* __restrict__ ad_,
    int M, int K) {
  __shared__ float As[32][68];   // 68 floats: rows 16B-aligned (17*16B)
  __shared__ float Bs[32][64];
  int tid = threadIdx.x;
  int m0 = blockIdx.x * 64;
  int n0 = blockIdx.y * 64;
  const float* Bp = B + (size_t)(n0 >> 7) * bskip;  // W_m1 row-chunk select
  int nb0 = n0 & 127;
  int tx = tid & 15, ty = tid >> 4;
  float acc[4][4] = {};
  for (int k0 = 0; k0 < K; k0 += 32) {
    const float* Asrc; int Alda; int kk;
    if (k0 < ksp) { Asrc = A;  Alda = lda;  kk = k0; }
    else          { Asrc = A2; Alda = lda2; kk = k0 - ksp; }
#pragma unroll
    for (int r = 0; r < 2; ++r) {   // A tile 64x32
      int m = (tid >> 3) + r * 32;
      int k = (tid & 7) * 4;
      float4 v = make_float4(0.f, 0.f, 0.f, 0.f);
      int gm = m0 + m;
      if (gm < M) v = *reinterpret_cast<const float4*>(&Asrc[(size_t)gm * Alda + kk + k]);
      As[k + 0][m] = v.x; As[k + 1][m] = v.y; As[k + 2][m] = v.z; As[k + 3][m] = v.w;
    }
#pragma unroll
    for (int r = 0; r < 2; ++r) {   // B tile 32x64
      int k = (tid >> 4) + r * 16;
      int nn = (tid & 15) * 4;
      float4 v = *reinterpret_cast<const float4*>(&Bp[(size_t)(k0 + k) * ldb + nb0 + nn]);
      *reinterpret_cast<float4*>(&Bs[k][nn]) = v;
    }
    __syncthreads();
#pragma unroll
    for (int k = 0; k < 32; ++k) {
      float a[4], b[4];
#pragma unroll
      for (int i = 0; i < 4; ++i) a[i] = As[k][ty * 4 + i];
#pragma unroll
      for (int i = 0; i < 4; ++i) b[i] = Bs[k][tx * 4 + i];
#pragma unroll
      for (int i = 0; i < 4; ++i)
#pragma unroll
        for (int j = 0; j < 4; ++j) acc[i][j] += a[i] * b[j];
    }
    __syncthreads();
  }
  float avv[4], bvv[4];
  if constexpr (SCORES) {
#pragma unroll
    for (int j = 0; j < 4; ++j) {
      avv[j] = av[n0 + tx * 4 + j];
      bvv[j] = bv[n0 + tx * 4 + j];
    }
  }
#pragma unroll
  for (int i = 0; i < 4; ++i) {
    int gm = m0 + ty * 4 + i;
    bool inb = gm < M;
    if (inb) {
      u16* bp = &Cb[(size_t)gm * ldcb + n0 + tx * 4];
      *reinterpret_cast<ushort4*>(bp) = make_ushort4(
          f2bf(acc[i][0]), f2bf(acc[i][1]), f2bf(acc[i][2]), f2bf(acc[i][3]));
    }
    if constexpr (SCORES) {
      float ps = acc[i][0] * avv[0] + acc[i][1] * avv[1] +
                 acc[i][2] * avv[2] + acc[i][3] * avv[3];
      float pd = acc[i][0] * bvv[0] + acc[i][1] * bvv[1] +
                 acc[i][2] * bvv[2] + acc[i][3] * bvv[3];
#pragma unroll
      for (int off = 1; off < 16; off <<= 1) {
        ps += __shfl_xor(ps, off, 16);
        pd += __shfl_xor(pd, off, 16);
      }
      if (tx == 0 && inb) {
        atomicAdd(&as_[gm], ps);
        atomicAdd(&ad_[gm], pd);
      }
    }
  }
}

// ---------------- GAT agg, D=128: 4 nodes/block, 2 edges in flight ---------

__global__ __launch_bounds__(256) void gat_agg1(
    const u16* __restrict__ hb, const float* __restrict__ as_,
    const float* __restrict__ ad_, const int* __restrict__ offs,
    const int* __restrict__ csr, const float* __restrict__ bias,
    float* __restrict__ out, int n) {
  int node = blockIdx.x * 4 + (threadIdx.x >> 6);
  if (node >= n) return;
  int lane = threadIdx.x & 63;
  int g = lane >> 5, sl = lane & 31;   // half-wave g, 4 cols per lane
  int beg = offs[node], end = offs[node + 1];
  float adn = ad_[node];
  float m = -1e30f;
  for (int i = beg + lane; i < end; i += 64) {
    float v = as_[csr[i]] + adn;
    v = (v > 0.f) ? v : 0.2f * v;
    m = fmaxf(m, v);
  }
#pragma unroll
  for (int off = 32; off; off >>= 1) m = fmaxf(m, __shfl_xor(m, off, 64));
  float denom = 0.f;
  float a[4] = {0.f, 0.f, 0.f, 0.f};
  // half-wave-strided serial loop, 1-deep pipeline
  int i = beg + g;
  int s = (i < end) ? csr[i] : -1;
  uint2 pv = make_uint2(0, 0); float e = 0.f;
  if (s >= 0) {
    pv = *reinterpret_cast<const uint2*>(&hb[(size_t)s * 128 + sl * 4]);
    e = as_[s] + adn;
  }
  while (s >= 0) {
    int i2 = i + 2;
    int s2 = (i2 < end) ? csr[i2] : -1;
    uint2 pv2 = make_uint2(0, 0); float e2 = 0.f;
    if (s2 >= 0) {
      pv2 = *reinterpret_cast<const uint2*>(&hb[(size_t)s2 * 128 + sl * 4]);
      e2 = as_[s2] + adn;
    }
    e = (e > 0.f) ? e : 0.2f * e;
    float wgt = __expf(e - m);
    denom += wgt;
    a[0] += wgt * bflo(pv.x); a[1] += wgt * bfhi(pv.x);
    a[2] += wgt * bflo(pv.y); a[3] += wgt * bfhi(pv.y);
    i = i2; s = s2; pv = pv2; e = e2;
  }
  denom += __shfl_xor(denom, 32, 64);
#pragma unroll
  for (int j = 0; j < 4; ++j) a[j] += __shfl_xor(a[j], 32, 64);
  if (g == 0) {
    float inv = 1.f / (denom + 1e-16f);
    float4 bv4 = *reinterpret_cast<const float4*>(&bias[sl * 4]);
    float4 o;
    o.x = fmaxf(a[0] * inv + bv4.x, 0.f);
    o.y = fmaxf(a[1] * inv + bv4.y, 0.f);
    o.z = fmaxf(a[2] * inv + bv4.z, 0.f);
    o.w = fmaxf(a[3] * inv + bv4.w, 0.f);
    *reinterpret_cast<float4*>(&out[(size_t)node * 128 + sl * 4]) = o;
  }
}

// ---------------- GAT agg, D=64: 4 nodes/block, 4 edges in flight ----------

__global__ __launch_bounds__(256) void gat_agg2(
    const u16* __restrict__ hb, const float* __restrict__ as_,
    const float* __restrict__ ad_, const int* __restrict__ offs,
    const int* __restrict__ csr, const float* __restrict__ bias,
    float* __restrict__ out, int n) {
  int node = blockIdx.x * 4 + (threadIdx.x >> 6);
  if (node >= n) return;
  int lane = threadIdx.x & 63;
  int g = lane >> 4, sl = lane & 15;   // quarter-wave g, 4 cols per lane
  int beg = offs[node], end = offs[node + 1];
  float adn = ad_[node];
  float m = -1e30f;
  for (int i = beg + lane; i < end; i += 64) {
    float v = as_[csr[i]] + adn;
    v = (v > 0.f) ? v : 0.2f * v;
    m = fmaxf(m, v);
  }
#pragma unroll
  for (int off = 32; off; off >>= 1) m = fmaxf(m, __shfl_xor(m, off, 64));
  float denom = 0.f;
  float a[4] = {0.f, 0.f, 0.f, 0.f};
  int i = beg + g;
  int s = (i < end) ? csr[i] : -1;
  uint2 pv = make_uint2(0, 0); float e = 0.f;
  if (s >= 0) {
    pv = *reinterpret_cast<const uint2*>(&hb[(size_t)s * 64 + sl * 4]);
    e = as_[s] + adn;
  }
  while (s >= 0) {
    int i2 = i + 4;
    int s2 = (i2 < end) ? csr[i2] : -1;
    uint2 pv2 = make_uint2(0, 0); float e2 = 0.f;
    if (s2 >= 0) {
      pv2 = *reinterpret_cast<const uint2*>(&hb[(size_t)s2 * 64 + sl * 4]);
      e2 = as_[s2] + adn;
    }
    e = (e > 0.f) ? e : 0.2f * e;
    float wgt = __expf(e - m);
    denom += wgt;
    a[0] += wgt * bflo(pv.x); a[1] += wgt * bfhi(pv.x);
    a[2] += wgt * bflo(pv.y); a[3] += wgt * bfhi(pv.y);
    i = i2; s = s2; pv = pv2; e = e2;
  }
  denom += __shfl_xor(denom, 16, 64);
  denom += __shfl_xor(denom, 32, 64);
#pragma unroll
  for (int j = 0; j < 4; ++j) {
    a[j] += __shfl_xor(a[j], 16, 64);
    a[j] += __shfl_xor(a[j], 32, 64);
  }
  if (lane < 16) {
    float inv = 1.f / (denom + 1e-16f);
    float4 bv4 = *reinterpret_cast<const float4*>(&bias[sl * 4]);
    float4 o;
    o.x = fmaxf(a[0] * inv + bv4.x, 0.f);
    o.y = fmaxf(a[1] * inv + bv4.y, 0.f);
    o.z = fmaxf(a[2] * inv + bv4.z, 0.f);
    o.w = fmaxf(a[3] * inv + bv4.w, 0.f);
    *reinterpret_cast<float4*>(&out[(size_t)node * 64 + sl * 4]) = o;
  }
}

// ---------------- fused edge MLP: 4 edges/wave, 16 lanes/edge --------------

__global__ __launch_bounds__(256) void edge_mlp(
    const int* __restrict__ eidx, const float* __restrict__ dist,
    const u16* __restrict__ Pb, const float* __restrict__ W3,
    const float* __restrict__ b1, const float* __restrict__ W2,
    const float* __restrict__ b2, float* __restrict__ out, int nE) {
  __shared__ float4 W3s[16][32];  // [k][q]: cols q*4..q*4+3
  int tid = threadIdx.x;
  for (int idx = tid; idx < 16 * 32; idx += 256) {
    int k = idx >> 5, q = idx & 31;
    W3s[k][q] = *reinterpret_cast<const float4*>(&W3[k * 128 + q * 4]);
  }
  __syncthreads();
  int lane = tid & 63, wv = tid >> 6;
  int g = lane >> 4, sl = lane & 15;   // edge slot g, 8 cols per lane
  float4 b1a = *reinterpret_cast<const float4*>(&b1[sl * 8]);
  float4 b1b = *reinterpret_cast<const float4*>(&b1[sl * 8 + 4]);
  float4 w2a = *reinterpret_cast<const float4*>(&W2[sl * 8]);
  float4 w2b = *reinterpret_cast<const float4*>(&W2[sl * 8 + 4]);
  float b2v = b2[0];
  for (int e0 = (blockIdx.x * 4 + wv) * 4; e0 < nE; e0 += gridDim.x * 16) {
    int e = e0 + g;
    bool valid = e < nE;
    int ee = valid ? e : 0;
    int r = eidx[2 * ee], c = eidx[2 * ee + 1];
    uint4 p1 = *reinterpret_cast<const uint4*>(&Pb[(size_t)r * 256 + sl * 8]);
    uint4 p2 = *reinterpret_cast<const uint4*>(&Pb[(size_t)c * 256 + 128 + sl * 8]);
    float dsl = dist[(size_t)ee * 16 + sl];
    float a[8];
    a[0] = bflo(p1.x) + bflo(p2.x) + b1a.x;
    a[1] = bfhi(p1.x) + bfhi(p2.x) + b1a.y;
    a[2] = bflo(p1.y) + bflo(p2.y) + b1a.z;
    a[3] = bfhi(p1.y) + bfhi(p2.y) + b1a.w;
    a[4] = bflo(p1.z) + bflo(p2.z) + b1b.x;
    a[5] = bfhi(p1.z) + bfhi(p2.z) + b1b.y;
    a[6] = bflo(p1.w) + bflo(p2.w) + b1b.z;
    a[7] = bfhi(p1.w) + bfhi(p2.w) + b1b.w;
#pragma unroll
    for (int k = 0; k < 16; ++k) {
      float dk = __shfl(dsl, (g << 4) + k, 64);
      float4 wA = W3s[k][2 * sl];
      float4 wB = W3s[k][2 * sl + 1];
      a[0] += dk * wA.x; a[1] += dk * wA.y; a[2] += dk * wA.z; a[3] += dk * wA.w;
      a[4] += dk * wB.x; a[5] += dk * wB.y; a[6] += dk * wB.z; a[7] += dk * wB.w;
    }
    float p = fmaxf(a[0], 0.f) * w2a.x + fmaxf(a[1], 0.f) * w2a.y +
              fmaxf(a[2], 0.f) * w2a.z + fmaxf(a[3], 0.f) * w2a.w +
              fmaxf(a[4], 0.f) * w2b.x + fmaxf(a[5], 0.f) * w2b.y +
              fmaxf(a[6], 0.f) * w2b.z + fmaxf(a[7], 0.f) * w2b.w;
#pragma unroll
    for (int off = 1; off < 16; off <<= 1) p += __shfl_xor(p, off, 16);
    if (valid && sl == 0) out[e] = 1.f / (1.f + __expf(-(p + b2v)));
  }
}

// ---------------- launch ---------------------------------------------------

extern "C" void kernel_launch(void* const* d_in, const int* in_sizes, int n_in,
                              void* d_out, int out_size, void* d_ws, size_t ws_size,
                              hipStream_t stream) {
  const float* x      = (const float*)d_in[0];
  const int*   eidx   = (const int*)d_in[1];
  const float* dist   = (const float*)d_in[2];
  const float* W_g1   = (const float*)d_in[3];
  const float* a1_src = (const float*)d_in[4];
  const float* a1_dst = (const float*)d_in[5];
  const float* b_g1   = (const float*)d_in[6];
  const float* W_g2   = (const float*)d_in[7];
  const float* a2_src = (const float*)d_in[8];
  const float* a2_dst = (const float*)d_in[9];
  const float* b_g2   = (const float*)d_in[10];
  const float* W_m1   = (const float*)d_in[11];
  const float* b_m1   = (const float*)d_in[12];
  const float* W_m2   = (const float*)d_in[13];
  const float* b_m2   = (const float*)d_in[14];
  float* out = (float*)d_out;

  const int n  = in_sizes[0] / GIN;   // 50000
  const int nE = in_sizes[1] / 2;     // 800000
  const int ndir = 2 * nE + n;        // 1,650,000

  char* w = (char*)d_ws;
  size_t off = 0;
  auto alloc = [&](size_t bytes) {
    size_t o = off;
    off += (bytes + 255) & ~(size_t)255;
    return o;
  };
  size_t o_deg    = alloc((size_t)n * 4);
  size_t o_offs   = alloc((size_t)(n + 1) * 4);
  size_t o_cursor = alloc((size_t)n * 4);
  size_t o_as1    = alloc((size_t)n * 4);
  size_t o_ad1    = alloc((size_t)n * 4);
  size_t o_as2    = alloc((size_t)n * 4);
  size_t o_ad2    = alloc((size_t)n * 4);
  size_t o_bsum   = alloc(64 * 4);
  size_t o_bscan  = alloc(64 * 4);
  size_t o_csr    = alloc((size_t)ndir * 4);
  size_t o_big    = alloc((size_t)n * 256 * 2);  // Pb; h1b/h2b overlay earlier
  size_t o_f1     = alloc((size_t)n * GHID * 4);
  size_t o_f2     = alloc((size_t)n * GOUT * 4);
  (void)ws_size;

  int*   deg    = (int*)(w + o_deg);
  int*   offs   = (int*)(w + o_offs);
  int*   cursor = (int*)(w + o_cursor);
  float* as1    = (float*)(w + o_as1);
  float* ad1    = (float*)(w + o_ad1);
  float* as2    = (float*)(w + o_as2);
  float* ad2    = (float*)(w + o_ad2);
  int*   bsum   = (int*)(w + o_bsum);
  int*   bscan  = (int*)(w + o_bscan);
  int*   csr    = (int*)(w + o_csr);
  u16*   h1b    = (u16*)(w + o_big);                          // dead after agg1
  u16*   h2b    = (u16*)(w + o_big + (size_t)n * GHID * 2);   // dead after agg2
  u16*   Pb     = (u16*)(w + o_big);                          // overlays h1b/h2b
  float* f1     = (float*)(w + o_f1);
  float* f2     = (float*)(w + o_f2);

  // 1. CSR build + score-accumulator zeroing
  hipMemsetAsync(deg, 0, (size_t)n * 4, stream);
  hipMemsetAsync(as1, 0, (size_t)n * 4, stream);
  hipMemsetAsync(ad1, 0, (size_t)n * 4, stream);
  hipMemsetAsync(as2, 0, (size_t)n * 4, stream);
  hipMemsetAsync(ad2, 0, (size_t)n * 4, stream);
  hist_kernel<<<2048, 256, 0, stream>>>(eidx, deg, nE, n);
  int nb = (n + SCAN_CHUNK - 1) / SCAN_CHUNK;  // 49 (<=64 required)
  scan_partial<<<nb, 256, 0, stream>>>(deg, bsum, n);
  scan_bsums<<<1, 64, 0, stream>>>(bsum, bscan, offs, nb, n);
  scan_final<<<nb, 256, 0, stream>>>(deg, bscan, offs, cursor, n);
  scatter_kernel<<<2048, 256, 0, stream>>>(eidx, cursor, csr, nE, n);

  const int mtiles = (n + 63) / 64;  // 782
  const int BIGK = 1 << 30;

  // 2. h1b = bf16(x @ W_g1), as1/ad1 fused
  gemm_bf<true><<<dim3(mtiles, 2), 256, 0, stream>>>(
      x, x, BIGK, GIN, GIN, W_g1, 0, GHID, h1b, GHID,
      a1_src, a1_dst, as1, ad1, n, GIN);

  // 3. f1 = relu(agg(h1b) + b_g1)
  gat_agg1<<<(n + 3) / 4, 256, 0, stream>>>(h1b, as1, ad1, offs, csr, b_g1, f1, n);

  // 4. h2b = bf16(f1 @ W_g2), as2/ad2 fused
  gemm_bf<true><<<dim3(mtiles, 1), 256, 0, stream>>>(
      f1, f1, BIGK, GHID, GHID, W_g2, 0, GOUT, h2b, GOUT,
      a2_src, a2_dst, as2, ad2, n, GHID);

  // 5. f2 = relu(agg(h2b) + b_g2)
  gat_agg2<<<(n + 3) / 4, 256, 0, stream>>>(h2b, as2, ad2, offs, csr, b_g2, f2, n);

  // 6. Pb = bf16([x|f2] @ W_m1[0:256]) — one dispatch, k-split A, B row-chunk
  gemm_bf<false><<<dim3(mtiles, 4), 256, 0, stream>>>(
      x, f2, GIN, GIN, GOUT, W_m1, 128 * 128, GHID, Pb, 256,
      nullptr, nullptr, nullptr, nullptr, n, GHID);

  // 7. fused edge MLP + sigmoid
  edge_mlp<<<4096, 256, 0, stream>>>(eidx, dist, Pb, W_m1 + 256 * 128, b_m1, W_m2, b_m2,
                                     out, nE);
}